// Round 1
// baseline (648.462 us; speedup 1.0000x reference)
//
#include <hip/hip_runtime.h>

#define T_TOK 16384
#define HDIM 2048
#define NEXP 12
#define FDIM 256
#define CAP 1707   // ceil(16384/12 * 1.25)

typedef __attribute__((ext_vector_type(8))) short short8;
typedef __attribute__((ext_vector_type(4))) float f32x4;

__device__ __forceinline__ unsigned short f2bf(float f) {
    unsigned int u = __float_as_uint(f);
    u += 0x7fffu + ((u >> 16) & 1u);   // RNE
    return (unsigned short)(u >> 16);
}

__device__ __forceinline__ void gload_lds16(const void* g, void* l) {
    __builtin_amdgcn_global_load_lds(
        (const __attribute__((address_space(1))) unsigned int*)g,
        (__attribute__((address_space(3))) unsigned int*)l, 16, 0, 0);
}

// ---------------- zero out ----------------
__global__ void zero_f4(float4* __restrict__ p, int n4) {
    int i = blockIdx.x * blockDim.x + threadIdx.x;
    int stride = gridDim.x * blockDim.x;
    float4 z = make_float4(0.f, 0.f, 0.f, 0.f);
    for (; i < n4; i += stride) p[i] = z;
}

// ---------------- fp32 -> bf16 convert ----------------
__global__ void cvt_bf16(const float4* __restrict__ src, ushort4* __restrict__ dst, int n4) {
    int i = blockIdx.x * blockDim.x + threadIdx.x;
    int stride = gridDim.x * blockDim.x;
    for (; i < n4; i += stride) {
        float4 v = src[i];
        ushort4 o;
        o.x = f2bf(v.x); o.y = f2bf(v.y); o.z = f2bf(v.z); o.w = f2bf(v.w);
        dst[i] = o;
    }
}

// ---------------- gating: partial logits (fp32) + xb (bf16) ----------------
// wave handles one K-chunk of 256 for 32 tokens.
// lane: eg = l>>4 (expert group: experts eg, eg+4, eg+8), kk = l&15.
__global__ __launch_bounds__(256) void gating_partial(
    const float* __restrict__ x, const float* __restrict__ gw,
    float* __restrict__ part, ushort4* __restrict__ xb4) {
    const int tid = threadIdx.x;
    const int wid = tid >> 6, l = tid & 63;
    const int c = blockIdx.y * 4 + wid;          // chunk 0..7
    const int eg = l >> 4, kk = l & 15;
    const int kbase = c * 256 + kk * 4;

    float4 g[3][4];
#pragma unroll
    for (int ei = 0; ei < 3; ei++) {
        int e = eg + ei * 4;
#pragma unroll
        for (int s = 0; s < 4; s++)
            g[ei][s] = *(const float4*)(gw + e * HDIM + kbase + s * 64);
    }

    const int t0 = blockIdx.x * 32;
    for (int tt = 0; tt < 32; tt++) {
        int t = t0 + tt;
        float a0 = 0.f, a1 = 0.f, a2 = 0.f;
#pragma unroll
        for (int s = 0; s < 4; s++) {
            float4 xv = *(const float4*)(x + (size_t)t * HDIM + kbase + s * 64);
            a0 = fmaf(g[0][s].x, xv.x, a0); a0 = fmaf(g[0][s].y, xv.y, a0);
            a0 = fmaf(g[0][s].z, xv.z, a0); a0 = fmaf(g[0][s].w, xv.w, a0);
            a1 = fmaf(g[1][s].x, xv.x, a1); a1 = fmaf(g[1][s].y, xv.y, a1);
            a1 = fmaf(g[1][s].z, xv.z, a1); a1 = fmaf(g[1][s].w, xv.w, a1);
            a2 = fmaf(g[2][s].x, xv.x, a2); a2 = fmaf(g[2][s].y, xv.y, a2);
            a2 = fmaf(g[2][s].z, xv.z, a2); a2 = fmaf(g[2][s].w, xv.w, a2);
            if (eg == 0) {  // fused x -> bf16 conversion (each (t,k) covered once)
                ushort4 o;
                o.x = f2bf(xv.x); o.y = f2bf(xv.y); o.z = f2bf(xv.z); o.w = f2bf(xv.w);
                xb4[((size_t)t * HDIM + kbase + s * 64) >> 2] = o;
            }
        }
#pragma unroll
        for (int m = 1; m < 16; m <<= 1) {   // reduce over kk (16 lanes)
            a0 += __shfl_xor(a0, m, 64);
            a1 += __shfl_xor(a1, m, 64);
            a2 += __shfl_xor(a2, m, 64);
        }
        if (kk == 0) {
            float* dst = part + ((size_t)c * T_TOK + t) * 12 + eg;
            dst[0] = a0; dst[4] = a1; dst[8] = a2;
        }
    }
}

// ---------------- top-2 + renormalized weights ----------------
__global__ void gating_top2(const float* __restrict__ part,
                            int* __restrict__ sel, float* __restrict__ rw) {
    int t = blockIdx.x * 256 + threadIdx.x;
    float lg[12];
#pragma unroll
    for (int e = 0; e < 12; e++) lg[e] = 0.f;
    for (int c = 0; c < 8; c++) {
        const float* p = part + ((size_t)c * T_TOK + t) * 12;
#pragma unroll
        for (int e = 0; e < 12; e++) lg[e] += p[e];
    }
    float m1 = -1e30f, m2 = -1e30f; int i1 = 0, i2 = 0;
#pragma unroll
    for (int e = 0; e < 12; e++) {
        float v = lg[e];
        if (v > m1) { m2 = m1; i2 = i1; m1 = v; i1 = e; }
        else if (v > m2) { m2 = v; i2 = e; }   // stable ties like lax.top_k
    }
    float r0 = 1.f / (1.f + expf(m2 - m1));   // p1/(p1+p2), softmax cancels
    sel[2 * t] = i1; sel[2 * t + 1] = i2;
    rw[2 * t] = r0;  rw[2 * t + 1] = 1.f - r0;
}

// ---------------- deterministic capacity routing (matches flat k*T+t order) ----------------
__global__ __launch_bounds__(1024) void routing_scan(
    const int* __restrict__ sel, const float* __restrict__ rw,
    int* __restrict__ tok, float* __restrict__ wgt) {
    const int e = blockIdx.x;
    const int tid = threadIdx.x;
    const int lane = tid & 63, w = tid >> 6;
    __shared__ int wsum[16];
    int running = 0;
    for (int it = 0; it < (2 * T_TOK) / 1024; it++) {
        int f = it * 1024 + tid;
        int k = f >> 14;              // slot (0 first, then 1) — slot-major order
        int t = f & (T_TOK - 1);
        bool m = (sel[2 * t + k] == e);
        unsigned long long mask = __ballot(m);
        if (lane == 0) wsum[w] = __popcll(mask);
        __syncthreads();
        int off = 0, tot = 0;
#pragma unroll
        for (int i = 0; i < 16; i++) {
            int v = wsum[i];
            tot += v;
            if (i < w) off += v;
        }
        if (m) {
            int pos = running + off + __popcll(mask & ((1ull << lane) - 1ull));
            if (pos < CAP) {
                tok[e * CAP + pos] = t;
                wgt[e * CAP + pos] = rw[2 * t + k];
            }
        }
        running += tot;
        __syncthreads();
    }
    for (int p = running + tid; p < CAP; p += 1024) {  // underfull expert padding
        tok[e * CAP + p] = 0;
        wgt[e * CAP + p] = 0.f;
    }
}

// ---------------- up-proj GEMM: G = silu((X@W1^T) * (X@W3^T)), bf16 out ----------------
// tile 128(M) x 64(N), K-step 32; A gathered via per-lane global addresses (tok_idx)
__global__ __launch_bounds__(256) void up_gemm(
    const unsigned short* __restrict__ xb,
    const unsigned short* __restrict__ w1b,
    const unsigned short* __restrict__ w3b,
    const int* __restrict__ tok,
    unsigned short* __restrict__ G) {
    __shared__ short As[128 * 32];
    __shared__ short B1s[64 * 32];
    __shared__ short B3s[64 * 32];
    const int e = blockIdx.z;
    const int cb = blockIdx.y * 64;
    const int m0 = blockIdx.x * 128;
    const int tid = threadIdx.x, wid = tid >> 6, l = tid & 63;

    const int ar0 = wid * 32 + (l >> 2);
    const int ar1 = ar0 + 16;
    const int tk0 = tok[e * CAP + min(m0 + ar0, CAP - 1)];
    const int tk1 = tok[e * CAP + min(m0 + ar1, CAP - 1)];
    const unsigned short* ga0 = xb + (size_t)tk0 * HDIM + (l & 3) * 8;
    const unsigned short* ga1 = xb + (size_t)tk1 * HDIM + (l & 3) * 8;
    const int bn = wid * 16 + (l >> 2);
    const unsigned short* gb1 = w1b + ((size_t)(e * FDIM + cb + bn)) * HDIM + (l & 3) * 8;
    const unsigned short* gb3 = w3b + ((size_t)(e * FDIM + cb + bn)) * HDIM + (l & 3) * 8;
    short* lA0 = As + (wid * 32) * 32;
    short* lA1 = As + (wid * 32 + 16) * 32;
    short* lB1 = B1s + (wid * 16) * 32;
    short* lB3 = B3s + (wid * 16) * 32;

    const int wm = wid & 1, wn = wid >> 1;
    const int mo = wm * 64, no = wn * 32;
    const int fr = l & 15, fq = l >> 4;

    const f32x4 zf = {0.f, 0.f, 0.f, 0.f};
    f32x4 acc1[4][2], acc3[4][2];
#pragma unroll
    for (int mt = 0; mt < 4; mt++)
#pragma unroll
        for (int nt = 0; nt < 2; nt++) { acc1[mt][nt] = zf; acc3[mt][nt] = zf; }

    for (int kt = 0; kt < HDIM / 32; kt++) {
        gload_lds16(ga0 + kt * 32, lA0);
        gload_lds16(ga1 + kt * 32, lA1);
        gload_lds16(gb1 + kt * 32, lB1);
        gload_lds16(gb3 + kt * 32, lB3);
        __syncthreads();
        short8 a[4], b1[2], b3[2];
#pragma unroll
        for (int mt = 0; mt < 4; mt++)
            a[mt] = *(const short8*)&As[(mo + mt * 16 + fr) * 32 + fq * 8];
#pragma unroll
        for (int nt = 0; nt < 2; nt++) {
            b1[nt] = *(const short8*)&B1s[(no + nt * 16 + fr) * 32 + fq * 8];
            b3[nt] = *(const short8*)&B3s[(no + nt * 16 + fr) * 32 + fq * 8];
        }
#pragma unroll
        for (int mt = 0; mt < 4; mt++)
#pragma unroll
            for (int nt = 0; nt < 2; nt++) {
                acc1[mt][nt] = __builtin_amdgcn_mfma_f32_16x16x32_bf16(a[mt], b1[nt], acc1[mt][nt], 0, 0, 0);
                acc3[mt][nt] = __builtin_amdgcn_mfma_f32_16x16x32_bf16(a[mt], b3[nt], acc3[mt][nt], 0, 0, 0);
            }
        __syncthreads();
    }
#pragma unroll
    for (int mt = 0; mt < 4; mt++)
#pragma unroll
        for (int i = 0; i < 4; i++) {
            int r = m0 + mo + mt * 16 + fq * 4 + i;
            if (r < CAP) {
                size_t base = ((size_t)e * CAP + r) * FDIM + cb + no;
#pragma unroll
                for (int nt = 0; nt < 2; nt++) {
                    float p = acc1[mt][nt][i] * acc3[mt][nt][i];  // silu applies to product
                    float gv = p / (1.f + __expf(-p));
                    G[base + nt * 16 + fr] = f2bf(gv);
                }
            }
        }
}

// ---------------- down-proj GEMM: out[tok] += (G @ W2^T) * wgt ----------------
__global__ __launch_bounds__(256) void down_gemm(
    const unsigned short* __restrict__ G,
    const unsigned short* __restrict__ w2b,
    const int* __restrict__ tok,
    const float* __restrict__ wgt,
    float* __restrict__ out) {
    __shared__ short As[128 * 32];
    __shared__ short Bs[128 * 32];
    const int e = blockIdx.z;
    const int n0 = blockIdx.y * 128;
    const int m0 = blockIdx.x * 128;
    const int tid = threadIdx.x, wid = tid >> 6, l = tid & 63;

    const int r0 = wid * 32 + (l >> 2);
    const int r1 = r0 + 16;
    const unsigned short* ga0 = G + ((size_t)e * CAP + min(m0 + r0, CAP - 1)) * FDIM + (l & 3) * 8;
    const unsigned short* ga1 = G + ((size_t)e * CAP + min(m0 + r1, CAP - 1)) * FDIM + (l & 3) * 8;
    const unsigned short* gb0 = w2b + ((size_t)(e * HDIM + n0 + r0)) * FDIM + (l & 3) * 8;
    const unsigned short* gb1 = w2b + ((size_t)(e * HDIM + n0 + r1)) * FDIM + (l & 3) * 8;
    short* lA0 = As + (wid * 32) * 32;
    short* lA1 = As + (wid * 32 + 16) * 32;
    short* lB0 = Bs + (wid * 32) * 32;
    short* lB1 = Bs + (wid * 32 + 16) * 32;

    const int wm = wid & 1, wn = wid >> 1;
    const int mo = wm * 64, no = wn * 64;
    const int fr = l & 15, fq = l >> 4;

    const f32x4 zf = {0.f, 0.f, 0.f, 0.f};
    f32x4 acc[4][4];
#pragma unroll
    for (int mt = 0; mt < 4; mt++)
#pragma unroll
        for (int nt = 0; nt < 4; nt++) acc[mt][nt] = zf;

    for (int kt = 0; kt < FDIM / 32; kt++) {
        gload_lds16(ga0 + kt * 32, lA0);
        gload_lds16(ga1 + kt * 32, lA1);
        gload_lds16(gb0 + kt * 32, lB0);
        gload_lds16(gb1 + kt * 32, lB1);
        __syncthreads();
        short8 a[4], b[4];
#pragma unroll
        for (int mt = 0; mt < 4; mt++)
            a[mt] = *(const short8*)&As[(mo + mt * 16 + fr) * 32 + fq * 8];
#pragma unroll
        for (int nt = 0; nt < 4; nt++)
            b[nt] = *(const short8*)&Bs[(no + nt * 16 + fr) * 32 + fq * 8];
#pragma unroll
        for (int mt = 0; mt < 4; mt++)
#pragma unroll
            for (int nt = 0; nt < 4; nt++)
                acc[mt][nt] = __builtin_amdgcn_mfma_f32_16x16x32_bf16(a[mt], b[nt], acc[mt][nt], 0, 0, 0);
        __syncthreads();
    }
#pragma unroll
    for (int mt = 0; mt < 4; mt++)
#pragma unroll
        for (int i = 0; i < 4; i++) {
            int r = m0 + mo + mt * 16 + fq * 4 + i;
            if (r < CAP) {
                float wv = wgt[e * CAP + r];
                if (wv != 0.f) {
                    int tk = tok[e * CAP + r];
                    float* orow = out + (size_t)tk * HDIM + n0 + no;
#pragma unroll
                    for (int nt = 0; nt < 4; nt++)
                        atomicAdd(&orow[nt * 16 + fr], acc[mt][nt][i] * wv);
                }
            }
        }
}

extern "C" void kernel_launch(void* const* d_in, const int* in_sizes, int n_in,
                              void* d_out, int out_size, void* d_ws, size_t ws_size,
                              hipStream_t stream) {
    const float* x  = (const float*)d_in[0];   // hidden_states (B,S,H) fp32
    const float* gw = (const float*)d_in[1];   // gate_w (E,H)
    const float* w1 = (const float*)d_in[2];   // (E,F,H)
    const float* w2 = (const float*)d_in[3];   // (E,H,F)
    const float* w3 = (const float*)d_in[4];   // (E,F,H)
    float* out = (float*)d_out;

    char* ws = (char*)d_ws;
    size_t off = 0;
    float* part = (float*)(ws + off);           off += (size_t)8 * T_TOK * 12 * 4;      // 6,291,456
    int* sel = (int*)(ws + off);                off += (size_t)T_TOK * 2 * 4;
    float* rw = (float*)(ws + off);             off += (size_t)T_TOK * 2 * 4;
    int* tok = (int*)(ws + off);                off += 82176;                            // 12*1707*4 padded
    float* wgt = (float*)(ws + off);            off += 82176;
    unsigned short* w1b = (unsigned short*)(ws + off); off += (size_t)NEXP * FDIM * HDIM * 2;
    unsigned short* w3b = (unsigned short*)(ws + off); off += (size_t)NEXP * FDIM * HDIM * 2;
    unsigned short* w2b = (unsigned short*)(ws + off); off += (size_t)NEXP * HDIM * FDIM * 2;
    unsigned short* xb  = (unsigned short*)(ws + off); off += (size_t)T_TOK * HDIM * 2;
    unsigned short* G   = (unsigned short*)(ws + off); off += (size_t)NEXP * CAP * FDIM * 2;
    // total ~122 MB

    const int nw4 = NEXP * FDIM * HDIM / 4;

    zero_f4<<<2048, 256, 0, stream>>>((float4*)out, T_TOK * HDIM / 4);
    cvt_bf16<<<1024, 256, 0, stream>>>((const float4*)w1, (ushort4*)w1b, nw4);
    cvt_bf16<<<1024, 256, 0, stream>>>((const float4*)w3, (ushort4*)w3b, nw4);
    cvt_bf16<<<1024, 256, 0, stream>>>((const float4*)w2, (ushort4*)w2b, nw4);
    gating_partial<<<dim3(T_TOK / 32, 2), 256, 0, stream>>>(x, gw, part, (ushort4*)xb);
    gating_top2<<<T_TOK / 256, 256, 0, stream>>>(part, sel, rw);
    routing_scan<<<NEXP, 1024, 0, stream>>>(sel, rw, tok, wgt);
    up_gemm<<<dim3(14, 4, NEXP), 256, 0, stream>>>(xb, w1b, w3b, tok, G);
    down_gemm<<<dim3(14, 16, NEXP), 256, 0, stream>>>(G, w2b, tok, wgt, out);
}

// Round 2
// 531.675 us; speedup vs baseline: 1.2197x; 1.2197x over previous
//
#include <hip/hip_runtime.h>

#define T_TOK 16384
#define HDIM 2048
#define NEXP 12
#define FDIM 256
#define CAP 1707   // ceil(16384/12 * 1.25)

typedef __attribute__((ext_vector_type(8))) short short8;
typedef __attribute__((ext_vector_type(8))) unsigned short ushort8v;
typedef __attribute__((ext_vector_type(4))) float f32x4;

__device__ __forceinline__ unsigned short f2bf(float f) {
    unsigned int u = __float_as_uint(f);
    u += 0x7fffu + ((u >> 16) & 1u);   // RNE
    return (unsigned short)(u >> 16);
}
__device__ __forceinline__ float bf2f(unsigned short u) {
    return __uint_as_float(((unsigned int)u) << 16);
}

__device__ __forceinline__ void gload_lds16(const void* g, void* l) {
    __builtin_amdgcn_global_load_lds(
        (const __attribute__((address_space(1))) unsigned int*)g,
        (__attribute__((address_space(3))) unsigned int*)l, 16, 0, 0);
}

// ---------------- fp32 -> bf16 convert ----------------
__global__ void cvt_bf16(const float4* __restrict__ src, ushort4* __restrict__ dst, int n4) {
    int i = blockIdx.x * blockDim.x + threadIdx.x;
    int stride = gridDim.x * blockDim.x;
    for (; i < n4; i += stride) {
        float4 v = src[i];
        ushort4 o;
        o.x = f2bf(v.x); o.y = f2bf(v.y); o.z = f2bf(v.z); o.w = f2bf(v.w);
        dst[i] = o;
    }
}

// ---------------- gating: partial logits (fp32) + xb (bf16) ----------------
__global__ __launch_bounds__(256) void gating_partial(
    const float* __restrict__ x, const float* __restrict__ gw,
    float* __restrict__ part, ushort4* __restrict__ xb4) {
    const int tid = threadIdx.x;
    const int wid = tid >> 6, l = tid & 63;
    const int c = blockIdx.y * 4 + wid;          // chunk 0..7
    const int eg = l >> 4, kk = l & 15;
    const int kbase = c * 256 + kk * 4;

    float4 g[3][4];
#pragma unroll
    for (int ei = 0; ei < 3; ei++) {
        int e = eg + ei * 4;
#pragma unroll
        for (int s = 0; s < 4; s++)
            g[ei][s] = *(const float4*)(gw + e * HDIM + kbase + s * 64);
    }

    const int t0 = blockIdx.x * 32;
    for (int tt = 0; tt < 32; tt++) {
        int t = t0 + tt;
        float a0 = 0.f, a1 = 0.f, a2 = 0.f;
#pragma unroll
        for (int s = 0; s < 4; s++) {
            float4 xv = *(const float4*)(x + (size_t)t * HDIM + kbase + s * 64);
            a0 = fmaf(g[0][s].x, xv.x, a0); a0 = fmaf(g[0][s].y, xv.y, a0);
            a0 = fmaf(g[0][s].z, xv.z, a0); a0 = fmaf(g[0][s].w, xv.w, a0);
            a1 = fmaf(g[1][s].x, xv.x, a1); a1 = fmaf(g[1][s].y, xv.y, a1);
            a1 = fmaf(g[1][s].z, xv.z, a1); a1 = fmaf(g[1][s].w, xv.w, a1);
            a2 = fmaf(g[2][s].x, xv.x, a2); a2 = fmaf(g[2][s].y, xv.y, a2);
            a2 = fmaf(g[2][s].z, xv.z, a2); a2 = fmaf(g[2][s].w, xv.w, a2);
            if (eg == 0) {  // fused x -> bf16 conversion
                ushort4 o;
                o.x = f2bf(xv.x); o.y = f2bf(xv.y); o.z = f2bf(xv.z); o.w = f2bf(xv.w);
                xb4[((size_t)t * HDIM + kbase + s * 64) >> 2] = o;
            }
        }
#pragma unroll
        for (int m = 1; m < 16; m <<= 1) {
            a0 += __shfl_xor(a0, m, 64);
            a1 += __shfl_xor(a1, m, 64);
            a2 += __shfl_xor(a2, m, 64);
        }
        if (kk == 0) {
            float* dst = part + ((size_t)c * T_TOK + t) * 12 + eg;
            dst[0] = a0; dst[4] = a1; dst[8] = a2;
        }
    }
}

// ---------------- top-2 + renormalized weights ----------------
__global__ void gating_top2(const float* __restrict__ part,
                            int* __restrict__ sel, float* __restrict__ rw) {
    int t = blockIdx.x * 256 + threadIdx.x;
    float lg[12];
#pragma unroll
    for (int e = 0; e < 12; e++) lg[e] = 0.f;
    for (int c = 0; c < 8; c++) {
        const float* p = part + ((size_t)c * T_TOK + t) * 12;
#pragma unroll
        for (int e = 0; e < 12; e++) lg[e] += p[e];
    }
    float m1 = -1e30f, m2 = -1e30f; int i1 = 0, i2 = 0;
#pragma unroll
    for (int e = 0; e < 12; e++) {
        float v = lg[e];
        if (v > m1) { m2 = m1; i2 = i1; m1 = v; i1 = e; }
        else if (v > m2) { m2 = v; i2 = e; }
    }
    float r0 = 1.f / (1.f + expf(m2 - m1));
    sel[2 * t] = i1; sel[2 * t + 1] = i2;
    rw[2 * t] = r0;  rw[2 * t + 1] = 1.f - r0;
}

// ---------------- routing: per-chunk expert histogram ----------------
__global__ __launch_bounds__(512) void route_count(const int* __restrict__ sel,
                                                   int* __restrict__ counts) {
    __shared__ int h[NEXP];
    if (threadIdx.x < NEXP) h[threadIdx.x] = 0;
    __syncthreads();
    int f = blockIdx.x * 512 + threadIdx.x;
    int k = f >> 14, t = f & (T_TOK - 1);
    atomicAdd(&h[sel[2 * t + k]], 1);
    __syncthreads();
    if (threadIdx.x < NEXP) counts[threadIdx.x * 64 + blockIdx.x] = h[threadIdx.x];
}

// ---------------- routing: emit slot assignments (slot-major flat order) ----------------
__global__ __launch_bounds__(512) void route_emit(const int* __restrict__ sel,
                                                  const int* __restrict__ counts,
                                                  int* __restrict__ tok,
                                                  int* __restrict__ loc) {
    const int e = blockIdx.y, c = blockIdx.x;
    const int tid = threadIdx.x, lane = tid & 63, w = tid >> 6;
    __shared__ int wsum[8];
    int base = 0;
    for (int i = 0; i < c; i++) base += counts[e * 64 + i];
    int f = c * 512 + tid;
    int k = f >> 14, t = f & (T_TOK - 1);
    bool m = (sel[2 * t + k] == e);
    unsigned long long mask = __ballot(m);
    if (lane == 0) wsum[w] = __popcll(mask);
    __syncthreads();
    int off = 0, tot = 0;
#pragma unroll
    for (int i = 0; i < 8; i++) { int v = wsum[i]; tot += v; if (i < w) off += v; }
    if (m) {
        int pos = base + off + __popcll(mask & ((1ull << lane) - 1ull));
        if (pos < CAP) { tok[e * CAP + pos] = t; loc[2 * t + k] = e * CAP + pos; }
        else loc[2 * t + k] = -1;
    }
    if (c == 63) {  // pad unfilled slots with a valid token index (never combined)
        int total = base + tot;
        for (int p = total + tid; p < CAP; p += 512) tok[e * CAP + p] = 0;
    }
}

// ---------------- up-proj GEMM: G = silu((X@W1^T)*(X@W3^T)), bf16 out ----------------
// operand-swapped MFMA: acc holds C^T so reg i spans 4 consecutive F-cols
__global__ __launch_bounds__(256) void up_gemm(
    const unsigned short* __restrict__ xb,
    const unsigned short* __restrict__ w1b,
    const unsigned short* __restrict__ w3b,
    const int* __restrict__ tok,
    unsigned short* __restrict__ G) {
    __shared__ short As[128 * 32];
    __shared__ short B1s[64 * 32];
    __shared__ short B3s[64 * 32];
    const int e = blockIdx.z;
    const int cb = blockIdx.y * 64;
    const int m0 = blockIdx.x * 128;
    const int tid = threadIdx.x, wid = tid >> 6, l = tid & 63;

    const int ar0 = wid * 32 + (l >> 2);
    const int ar1 = ar0 + 16;
    const int tk0 = tok[e * CAP + min(m0 + ar0, CAP - 1)];
    const int tk1 = tok[e * CAP + min(m0 + ar1, CAP - 1)];
    const unsigned short* ga0 = xb + (size_t)tk0 * HDIM + (l & 3) * 8;
    const unsigned short* ga1 = xb + (size_t)tk1 * HDIM + (l & 3) * 8;
    const int bn = wid * 16 + (l >> 2);
    const unsigned short* gb1 = w1b + ((size_t)(e * FDIM + cb + bn)) * HDIM + (l & 3) * 8;
    const unsigned short* gb3 = w3b + ((size_t)(e * FDIM + cb + bn)) * HDIM + (l & 3) * 8;
    short* lA0 = As + (wid * 32) * 32;
    short* lA1 = As + (wid * 32 + 16) * 32;
    short* lB1 = B1s + (wid * 16) * 32;
    short* lB3 = B3s + (wid * 16) * 32;

    const int wm = wid & 1, wn = wid >> 1;
    const int mo = wm * 64, no = wn * 32;
    const int fr = l & 15, fq = l >> 4;

    const f32x4 zf = {0.f, 0.f, 0.f, 0.f};
    f32x4 acc1[2][4], acc3[2][4];   // [nt][mt], transposed product
#pragma unroll
    for (int nt = 0; nt < 2; nt++)
#pragma unroll
        for (int mt = 0; mt < 4; mt++) { acc1[nt][mt] = zf; acc3[nt][mt] = zf; }

    for (int kt = 0; kt < HDIM / 32; kt++) {
        gload_lds16(ga0 + kt * 32, lA0);
        gload_lds16(ga1 + kt * 32, lA1);
        gload_lds16(gb1 + kt * 32, lB1);
        gload_lds16(gb3 + kt * 32, lB3);
        __syncthreads();
        short8 a[4], b1[2], b3[2];
#pragma unroll
        for (int mt = 0; mt < 4; mt++)
            a[mt] = *(const short8*)&As[(mo + mt * 16 + fr) * 32 + fq * 8];
#pragma unroll
        for (int nt = 0; nt < 2; nt++) {
            b1[nt] = *(const short8*)&B1s[(no + nt * 16 + fr) * 32 + fq * 8];
            b3[nt] = *(const short8*)&B3s[(no + nt * 16 + fr) * 32 + fq * 8];
        }
#pragma unroll
        for (int nt = 0; nt < 2; nt++)
#pragma unroll
            for (int mt = 0; mt < 4; mt++) {
                acc1[nt][mt] = __builtin_amdgcn_mfma_f32_16x16x32_bf16(b1[nt], a[mt], acc1[nt][mt], 0, 0, 0);
                acc3[nt][mt] = __builtin_amdgcn_mfma_f32_16x16x32_bf16(b3[nt], a[mt], acc3[nt][mt], 0, 0, 0);
            }
        __syncthreads();
    }
    // epilogue: thread holds rows r = mo+mt*16+fr (slot), cols cb+no+nt*16+fq*4+i
#pragma unroll
    for (int mt = 0; mt < 4; mt++) {
        int r = m0 + mo + mt * 16 + fr;
        if (r < CAP) {
            size_t base = ((size_t)e * CAP + r) * FDIM + cb + no;
#pragma unroll
            for (int nt = 0; nt < 2; nt++) {
                ushort4 o;
                float p;
                p = acc1[nt][mt][0] * acc3[nt][mt][0]; o.x = f2bf(p / (1.f + __expf(-p)));
                p = acc1[nt][mt][1] * acc3[nt][mt][1]; o.y = f2bf(p / (1.f + __expf(-p)));
                p = acc1[nt][mt][2] * acc3[nt][mt][2]; o.z = f2bf(p / (1.f + __expf(-p)));
                p = acc1[nt][mt][3] * acc3[nt][mt][3]; o.w = f2bf(p / (1.f + __expf(-p)));
                *(ushort4*)&G[base + nt * 16 + fq * 4] = o;
            }
        }
    }
}

// ---------------- down-proj GEMM: D[slot] = G[slot] @ W2^T, bf16, NO atomics ----------------
__global__ __launch_bounds__(256) void down_gemm(
    const unsigned short* __restrict__ G,
    const unsigned short* __restrict__ w2b,
    unsigned short* __restrict__ D) {
    __shared__ short As[128 * 32];
    __shared__ short Bs[128 * 32];
    const int e = blockIdx.z;
    const int n0 = blockIdx.y * 128;
    const int m0 = blockIdx.x * 128;
    const int tid = threadIdx.x, wid = tid >> 6, l = tid & 63;

    const int r0 = wid * 32 + (l >> 2);
    const int r1 = r0 + 16;
    const unsigned short* ga0 = G + ((size_t)e * CAP + min(m0 + r0, CAP - 1)) * FDIM + (l & 3) * 8;
    const unsigned short* ga1 = G + ((size_t)e * CAP + min(m0 + r1, CAP - 1)) * FDIM + (l & 3) * 8;
    const unsigned short* gb0 = w2b + ((size_t)(e * HDIM + n0 + r0)) * FDIM + (l & 3) * 8;
    const unsigned short* gb1 = w2b + ((size_t)(e * HDIM + n0 + r1)) * FDIM + (l & 3) * 8;
    short* lA0 = As + (wid * 32) * 32;
    short* lA1 = As + (wid * 32 + 16) * 32;
    short* lB0 = Bs + (wid * 32) * 32;
    short* lB1 = Bs + (wid * 32 + 16) * 32;

    const int wm = wid & 1, wn = wid >> 1;
    const int mo = wm * 64, no = wn * 64;
    const int fr = l & 15, fq = l >> 4;

    const f32x4 zf = {0.f, 0.f, 0.f, 0.f};
    f32x4 acc[4][4];   // [nt][mt], transposed product
#pragma unroll
    for (int nt = 0; nt < 4; nt++)
#pragma unroll
        for (int mt = 0; mt < 4; mt++) acc[nt][mt] = zf;

    for (int kt = 0; kt < FDIM / 32; kt++) {
        gload_lds16(ga0 + kt * 32, lA0);
        gload_lds16(ga1 + kt * 32, lA1);
        gload_lds16(gb0 + kt * 32, lB0);
        gload_lds16(gb1 + kt * 32, lB1);
        __syncthreads();
        short8 a[4], b[4];
#pragma unroll
        for (int mt = 0; mt < 4; mt++)
            a[mt] = *(const short8*)&As[(mo + mt * 16 + fr) * 32 + fq * 8];
#pragma unroll
        for (int nt = 0; nt < 4; nt++)
            b[nt] = *(const short8*)&Bs[(no + nt * 16 + fr) * 32 + fq * 8];
#pragma unroll
        for (int nt = 0; nt < 4; nt++)
#pragma unroll
            for (int mt = 0; mt < 4; mt++)
                acc[nt][mt] = __builtin_amdgcn_mfma_f32_16x16x32_bf16(b[nt], a[mt], acc[nt][mt], 0, 0, 0);
        __syncthreads();
    }
    // thread holds rows r = mo+mt*16+fr (slot), cols n0+no+nt*16+fq*4+i (H)
#pragma unroll
    for (int mt = 0; mt < 4; mt++) {
        int r = m0 + mo + mt * 16 + fr;
        if (r < CAP) {
            size_t base = ((size_t)e * CAP + r) * HDIM + n0 + no;
#pragma unroll
            for (int nt = 0; nt < 4; nt++) {
                ushort4 o;
                o.x = f2bf(acc[nt][mt][0]);
                o.y = f2bf(acc[nt][mt][1]);
                o.z = f2bf(acc[nt][mt][2]);
                o.w = f2bf(acc[nt][mt][3]);
                *(ushort4*)&D[base + nt * 16 + fq * 4] = o;
            }
        }
    }
}

// ---------------- combine: out[t] = w0*D[loc0] + w1*D[loc1] ----------------
__global__ __launch_bounds__(256) void combine(const unsigned short* __restrict__ D,
                                               const int* __restrict__ loc,
                                               const float* __restrict__ rw,
                                               float* __restrict__ out) {
    const int t = blockIdx.x;
    const int h = threadIdx.x * 8;
    const int l0 = loc[2 * t], l1 = loc[2 * t + 1];
    const float w0 = rw[2 * t], w1 = rw[2 * t + 1];
    float acc[8];
#pragma unroll
    for (int i = 0; i < 8; i++) acc[i] = 0.f;
    if (l0 >= 0) {
        ushort8v v = *(const ushort8v*)&D[(size_t)l0 * HDIM + h];
#pragma unroll
        for (int i = 0; i < 8; i++) acc[i] = w0 * bf2f(v[i]);
    }
    if (l1 >= 0) {
        ushort8v v = *(const ushort8v*)&D[(size_t)l1 * HDIM + h];
#pragma unroll
        for (int i = 0; i < 8; i++) acc[i] += w1 * bf2f(v[i]);
    }
    float4 o0 = make_float4(acc[0], acc[1], acc[2], acc[3]);
    float4 o1 = make_float4(acc[4], acc[5], acc[6], acc[7]);
    *(float4*)&out[(size_t)t * HDIM + h] = o0;
    *(float4*)&out[(size_t)t * HDIM + h + 4] = o1;
}

extern "C" void kernel_launch(void* const* d_in, const int* in_sizes, int n_in,
                              void* d_out, int out_size, void* d_ws, size_t ws_size,
                              hipStream_t stream) {
    const float* x  = (const float*)d_in[0];
    const float* gw = (const float*)d_in[1];
    const float* w1 = (const float*)d_in[2];
    const float* w2 = (const float*)d_in[3];
    const float* w3 = (const float*)d_in[4];
    float* out = (float*)d_out;

    char* ws = (char*)d_ws;
    size_t off = 0;
    int* sel = (int*)(ws + off);                off += (size_t)T_TOK * 2 * 4;   // 128K
    int* loc = (int*)(ws + off);                off += (size_t)T_TOK * 2 * 4;   // 128K
    float* rw = (float*)(ws + off);             off += (size_t)T_TOK * 2 * 4;   // 128K
    int* tok = (int*)(ws + off);                off += 82176;                    // 12*1707*4 padded
    int* counts = (int*)(ws + off);             off += 4096;                     // 12*64*4 padded
    unsigned short* w2b = (unsigned short*)(ws + off); off += (size_t)NEXP * HDIM * FDIM * 2;
    unsigned short* G   = (unsigned short*)(ws + off); off += (size_t)NEXP * CAP * FDIM * 2;
    // aliased region R (98.5 MB): phase 1 = part+w1b+w3b+xb; phase 2 = D (84 MB)
    char* R = ws + off;
    float* part = (float*)R;                                                    // 6,291,456 B
    unsigned short* w1b = (unsigned short*)(R + 6291456);                       // 12,582,912 B
    unsigned short* w3b = (unsigned short*)(R + 6291456 + 12582912);            // 12,582,912 B
    unsigned short* xb  = (unsigned short*)(R + 6291456 + 2 * 12582912);        // 67,108,864 B
    unsigned short* D   = (unsigned short*)R;                                   // 83,902,464 B

    const int nw4 = NEXP * FDIM * HDIM / 4;

    cvt_bf16<<<1024, 256, 0, stream>>>((const float4*)w1, (ushort4*)w1b, nw4);
    cvt_bf16<<<1024, 256, 0, stream>>>((const float4*)w3, (ushort4*)w3b, nw4);
    cvt_bf16<<<1024, 256, 0, stream>>>((const float4*)w2, (ushort4*)w2b, nw4);
    gating_partial<<<dim3(T_TOK / 32, 2), 256, 0, stream>>>(x, gw, part, (ushort4*)xb);
    gating_top2<<<T_TOK / 256, 256, 0, stream>>>(part, sel, rw);
    route_count<<<64, 512, 0, stream>>>(sel, counts);
    route_emit<<<dim3(64, NEXP), 512, 0, stream>>>(sel, counts, tok, loc);
    up_gemm<<<dim3(14, 4, NEXP), 256, 0, stream>>>(xb, w1b, w3b, tok, G);
    down_gemm<<<dim3(14, 16, NEXP), 256, 0, stream>>>(G, w2b, D);
    combine<<<T_TOK, 256, 0, stream>>>(D, loc, rw, out);
}

// Round 3
// 512.860 us; speedup vs baseline: 1.2644x; 1.0367x over previous
//
#include <hip/hip_runtime.h>

#define T_TOK 16384
#define HDIM 2048
#define NEXP 12
#define FDIM 256
#define CAP 1707   // ceil(16384/12 * 1.25)

typedef __attribute__((ext_vector_type(8))) short short8;
typedef __attribute__((ext_vector_type(8))) unsigned short ushort8v;
typedef __attribute__((ext_vector_type(4))) float f32x4;

__device__ __forceinline__ unsigned short f2bf(float f) {
    unsigned int u = __float_as_uint(f);
    u += 0x7fffu + ((u >> 16) & 1u);   // RNE
    return (unsigned short)(u >> 16);
}
__device__ __forceinline__ float bf2f(unsigned short u) {
    return __uint_as_float(((unsigned int)u) << 16);
}

__device__ __forceinline__ void gload_lds16(const void* g, void* l) {
    __builtin_amdgcn_global_load_lds(
        (const __attribute__((address_space(1))) unsigned int*)g,
        (__attribute__((address_space(3))) unsigned int*)l, 16, 0, 0);
}

// ---------------- fp32 -> bf16 convert, all three weights in one launch ----------------
__global__ void cvt3(const float4* __restrict__ s0, ushort4* __restrict__ d0,
                     const float4* __restrict__ s1, ushort4* __restrict__ d1,
                     const float4* __restrict__ s2, ushort4* __restrict__ d2, int n4) {
    int i = blockIdx.x * blockDim.x + threadIdx.x;
    int stride = gridDim.x * blockDim.x;
    for (; i < 3 * n4; i += stride) {
        const float4* s; ushort4* d; int j;
        if (i < n4)            { s = s0; d = d0; j = i; }
        else if (i < 2 * n4)   { s = s1; d = d1; j = i - n4; }
        else                   { s = s2; d = d2; j = i - 2 * n4; }
        float4 v = s[j];
        ushort4 o;
        o.x = f2bf(v.x); o.y = f2bf(v.y); o.z = f2bf(v.z); o.w = f2bf(v.w);
        d[j] = o;
    }
}

// ---------------- gating: partial logits (fp32) + xb (bf16) ----------------
// wave handles one K-chunk of 256 for 8 tokens (2 in flight for ILP).
// lane: eg = l>>4 (expert group: experts eg, eg+4, eg+8), kk = l&15.
__global__ __launch_bounds__(256) void gating_partial(
    const float* __restrict__ x, const float* __restrict__ gw,
    float* __restrict__ part, ushort4* __restrict__ xb4) {
    const int tid = threadIdx.x;
    const int wid = tid >> 6, l = tid & 63;
    const int c = blockIdx.y * 4 + wid;          // chunk 0..7
    const int eg = l >> 4, kk = l & 15;
    const int kbase = c * 256 + kk * 4;

    float4 g[3][4];
#pragma unroll
    for (int ei = 0; ei < 3; ei++) {
        int e = eg + ei * 4;
#pragma unroll
        for (int s = 0; s < 4; s++)
            g[ei][s] = *(const float4*)(gw + e * HDIM + kbase + s * 64);
    }

    const int t0 = blockIdx.x * 8;
    for (int tt = 0; tt < 8; tt += 2) {
        float a[2][3];
#pragma unroll
        for (int u = 0; u < 2; u++)
#pragma unroll
            for (int e = 0; e < 3; e++) a[u][e] = 0.f;
#pragma unroll
        for (int s = 0; s < 4; s++) {
            float4 xv[2];
#pragma unroll
            for (int u = 0; u < 2; u++)
                xv[u] = *(const float4*)(x + (size_t)(t0 + tt + u) * HDIM + kbase + s * 64);
#pragma unroll
            for (int u = 0; u < 2; u++) {
                a[u][0] = fmaf(g[0][s].x, xv[u].x, a[u][0]); a[u][0] = fmaf(g[0][s].y, xv[u].y, a[u][0]);
                a[u][0] = fmaf(g[0][s].z, xv[u].z, a[u][0]); a[u][0] = fmaf(g[0][s].w, xv[u].w, a[u][0]);
                a[u][1] = fmaf(g[1][s].x, xv[u].x, a[u][1]); a[u][1] = fmaf(g[1][s].y, xv[u].y, a[u][1]);
                a[u][1] = fmaf(g[1][s].z, xv[u].z, a[u][1]); a[u][1] = fmaf(g[1][s].w, xv[u].w, a[u][1]);
                a[u][2] = fmaf(g[2][s].x, xv[u].x, a[u][2]); a[u][2] = fmaf(g[2][s].y, xv[u].y, a[u][2]);
                a[u][2] = fmaf(g[2][s].z, xv[u].z, a[u][2]); a[u][2] = fmaf(g[2][s].w, xv[u].w, a[u][2]);
                if (eg == 0) {  // fused x -> bf16 conversion (each (t,k) covered once)
                    ushort4 o;
                    o.x = f2bf(xv[u].x); o.y = f2bf(xv[u].y);
                    o.z = f2bf(xv[u].z); o.w = f2bf(xv[u].w);
                    xb4[((size_t)(t0 + tt + u) * HDIM + kbase + s * 64) >> 2] = o;
                }
            }
        }
#pragma unroll
        for (int m = 1; m < 16; m <<= 1) {   // reduce over kk (16 lanes), 6 chains in flight
#pragma unroll
            for (int u = 0; u < 2; u++) {
                a[u][0] += __shfl_xor(a[u][0], m, 64);
                a[u][1] += __shfl_xor(a[u][1], m, 64);
                a[u][2] += __shfl_xor(a[u][2], m, 64);
            }
        }
        if (kk == 0) {
#pragma unroll
            for (int u = 0; u < 2; u++) {
                float* dst = part + ((size_t)c * T_TOK + t0 + tt + u) * 12 + eg;
                dst[0] = a[u][0]; dst[4] = a[u][1]; dst[8] = a[u][2];
            }
        }
    }
}

// ---------------- top-2 + renormalized weights ----------------
__global__ void gating_top2(const float* __restrict__ part,
                            int* __restrict__ sel, float* __restrict__ rw) {
    int t = blockIdx.x * 256 + threadIdx.x;
    float lg[12];
#pragma unroll
    for (int e = 0; e < 12; e++) lg[e] = 0.f;
    for (int c = 0; c < 8; c++) {
        const float* p = part + ((size_t)c * T_TOK + t) * 12;
#pragma unroll
        for (int e = 0; e < 12; e++) lg[e] += p[e];
    }
    float m1 = -1e30f, m2 = -1e30f; int i1 = 0, i2 = 0;
#pragma unroll
    for (int e = 0; e < 12; e++) {
        float v = lg[e];
        if (v > m1) { m2 = m1; i2 = i1; m1 = v; i1 = e; }
        else if (v > m2) { m2 = v; i2 = e; }
    }
    float r0 = 1.f / (1.f + expf(m2 - m1));
    sel[2 * t] = i1; sel[2 * t + 1] = i2;
    rw[2 * t] = r0;  rw[2 * t + 1] = 1.f - r0;
}

// ---------------- routing: per-chunk expert histogram ----------------
__global__ __launch_bounds__(512) void route_count(const int* __restrict__ sel,
                                                   int* __restrict__ counts) {
    __shared__ int h[NEXP];
    if (threadIdx.x < NEXP) h[threadIdx.x] = 0;
    __syncthreads();
    int f = blockIdx.x * 512 + threadIdx.x;
    int k = f >> 14, t = f & (T_TOK - 1);
    atomicAdd(&h[sel[2 * t + k]], 1);
    __syncthreads();
    if (threadIdx.x < NEXP) counts[threadIdx.x * 64 + blockIdx.x] = h[threadIdx.x];
}

// ---------------- routing: emit slot assignments (slot-major flat order) ----------------
__global__ __launch_bounds__(512) void route_emit(const int* __restrict__ sel,
                                                  const int* __restrict__ counts,
                                                  int* __restrict__ tok,
                                                  int* __restrict__ loc) {
    const int e = blockIdx.y, c = blockIdx.x;
    const int tid = threadIdx.x, lane = tid & 63, w = tid >> 6;
    __shared__ int wsum[8];
    int base = 0;
    for (int i = 0; i < c; i++) base += counts[e * 64 + i];
    int f = c * 512 + tid;
    int k = f >> 14, t = f & (T_TOK - 1);
    bool m = (sel[2 * t + k] == e);
    unsigned long long mask = __ballot(m);
    if (lane == 0) wsum[w] = __popcll(mask);
    __syncthreads();
    int off = 0, tot = 0;
#pragma unroll
    for (int i = 0; i < 8; i++) { int v = wsum[i]; tot += v; if (i < w) off += v; }
    if (m) {
        int pos = base + off + __popcll(mask & ((1ull << lane) - 1ull));
        if (pos < CAP) { tok[e * CAP + pos] = t; loc[2 * t + k] = e * CAP + pos; }
        else loc[2 * t + k] = -1;
    }
    if (c == 63) {  // pad unfilled slots with a valid token index (never combined)
        int total = base + tot;
        for (int p = total + tid; p < CAP; p += 512) tok[e * CAP + p] = 0;
    }
}

// ---------------- up-proj GEMM: G = silu((X@W1^T)*(X@W3^T)), bf16 out ----------------
// operand-swapped MFMA: acc holds C^T so reg i spans 4 consecutive F-cols
__global__ __launch_bounds__(256) void up_gemm(
    const unsigned short* __restrict__ xb,
    const unsigned short* __restrict__ w1b,
    const unsigned short* __restrict__ w3b,
    const int* __restrict__ tok,
    unsigned short* __restrict__ G) {
    __shared__ short As[128 * 32];
    __shared__ short B1s[64 * 32];
    __shared__ short B3s[64 * 32];
    const int e = blockIdx.z;
    const int cb = blockIdx.y * 64;
    const int m0 = blockIdx.x * 128;
    const int tid = threadIdx.x, wid = tid >> 6, l = tid & 63;

    const int ar0 = wid * 32 + (l >> 2);
    const int ar1 = ar0 + 16;
    const int tk0 = tok[e * CAP + min(m0 + ar0, CAP - 1)];
    const int tk1 = tok[e * CAP + min(m0 + ar1, CAP - 1)];
    const unsigned short* ga0 = xb + (size_t)tk0 * HDIM + (l & 3) * 8;
    const unsigned short* ga1 = xb + (size_t)tk1 * HDIM + (l & 3) * 8;
    const int bn = wid * 16 + (l >> 2);
    const unsigned short* gb1 = w1b + ((size_t)(e * FDIM + cb + bn)) * HDIM + (l & 3) * 8;
    const unsigned short* gb3 = w3b + ((size_t)(e * FDIM + cb + bn)) * HDIM + (l & 3) * 8;
    short* lA0 = As + (wid * 32) * 32;
    short* lA1 = As + (wid * 32 + 16) * 32;
    short* lB1 = B1s + (wid * 16) * 32;
    short* lB3 = B3s + (wid * 16) * 32;

    const int wm = wid & 1, wn = wid >> 1;
    const int mo = wm * 64, no = wn * 32;
    const int fr = l & 15, fq = l >> 4;

    const f32x4 zf = {0.f, 0.f, 0.f, 0.f};
    f32x4 acc1[2][4], acc3[2][4];   // [nt][mt], transposed product
#pragma unroll
    for (int nt = 0; nt < 2; nt++)
#pragma unroll
        for (int mt = 0; mt < 4; mt++) { acc1[nt][mt] = zf; acc3[nt][mt] = zf; }

    for (int kt = 0; kt < HDIM / 32; kt++) {
        gload_lds16(ga0 + kt * 32, lA0);
        gload_lds16(ga1 + kt * 32, lA1);
        gload_lds16(gb1 + kt * 32, lB1);
        gload_lds16(gb3 + kt * 32, lB3);
        __syncthreads();
        short8 a[4], b1[2], b3[2];
#pragma unroll
        for (int mt = 0; mt < 4; mt++)
            a[mt] = *(const short8*)&As[(mo + mt * 16 + fr) * 32 + fq * 8];
#pragma unroll
        for (int nt = 0; nt < 2; nt++) {
            b1[nt] = *(const short8*)&B1s[(no + nt * 16 + fr) * 32 + fq * 8];
            b3[nt] = *(const short8*)&B3s[(no + nt * 16 + fr) * 32 + fq * 8];
        }
#pragma unroll
        for (int nt = 0; nt < 2; nt++)
#pragma unroll
            for (int mt = 0; mt < 4; mt++) {
                acc1[nt][mt] = __builtin_amdgcn_mfma_f32_16x16x32_bf16(b1[nt], a[mt], acc1[nt][mt], 0, 0, 0);
                acc3[nt][mt] = __builtin_amdgcn_mfma_f32_16x16x32_bf16(b3[nt], a[mt], acc3[nt][mt], 0, 0, 0);
            }
        __syncthreads();
    }
    // epilogue: thread holds rows r = mo+mt*16+fr (slot), cols cb+no+nt*16+fq*4+i
#pragma unroll
    for (int mt = 0; mt < 4; mt++) {
        int r = m0 + mo + mt * 16 + fr;
        if (r < CAP) {
            size_t base = ((size_t)e * CAP + r) * FDIM + cb + no;
#pragma unroll
            for (int nt = 0; nt < 2; nt++) {
                ushort4 o;
                float p;
                p = acc1[nt][mt][0] * acc3[nt][mt][0]; o.x = f2bf(p / (1.f + __expf(-p)));
                p = acc1[nt][mt][1] * acc3[nt][mt][1]; o.y = f2bf(p / (1.f + __expf(-p)));
                p = acc1[nt][mt][2] * acc3[nt][mt][2]; o.z = f2bf(p / (1.f + __expf(-p)));
                p = acc1[nt][mt][3] * acc3[nt][mt][3]; o.w = f2bf(p / (1.f + __expf(-p)));
                *(ushort4*)&G[base + nt * 16 + fq * 4] = o;
            }
        }
    }
}

// ---------------- down-proj GEMM: D[slot] = G[slot] @ W2^T, bf16, NO atomics ----------------
__global__ __launch_bounds__(256) void down_gemm(
    const unsigned short* __restrict__ G,
    const unsigned short* __restrict__ w2b,
    unsigned short* __restrict__ D) {
    __shared__ short As[128 * 32];
    __shared__ short Bs[128 * 32];
    const int e = blockIdx.z;
    const int n0 = blockIdx.y * 128;
    const int m0 = blockIdx.x * 128;
    const int tid = threadIdx.x, wid = tid >> 6, l = tid & 63;

    const int r0 = wid * 32 + (l >> 2);
    const int r1 = r0 + 16;
    const unsigned short* ga0 = G + ((size_t)e * CAP + min(m0 + r0, CAP - 1)) * FDIM + (l & 3) * 8;
    const unsigned short* ga1 = G + ((size_t)e * CAP + min(m0 + r1, CAP - 1)) * FDIM + (l & 3) * 8;
    const unsigned short* gb0 = w2b + ((size_t)(e * HDIM + n0 + r0)) * FDIM + (l & 3) * 8;
    const unsigned short* gb1 = w2b + ((size_t)(e * HDIM + n0 + r1)) * FDIM + (l & 3) * 8;
    short* lA0 = As + (wid * 32) * 32;
    short* lA1 = As + (wid * 32 + 16) * 32;
    short* lB0 = Bs + (wid * 32) * 32;
    short* lB1 = Bs + (wid * 32 + 16) * 32;

    const int wm = wid & 1, wn = wid >> 1;
    const int mo = wm * 64, no = wn * 64;
    const int fr = l & 15, fq = l >> 4;

    const f32x4 zf = {0.f, 0.f, 0.f, 0.f};
    f32x4 acc[4][4];   // [nt][mt], transposed product
#pragma unroll
    for (int nt = 0; nt < 4; nt++)
#pragma unroll
        for (int mt = 0; mt < 4; mt++) acc[nt][mt] = zf;

    for (int kt = 0; kt < FDIM / 32; kt++) {
        gload_lds16(ga0 + kt * 32, lA0);
        gload_lds16(ga1 + kt * 32, lA1);
        gload_lds16(gb0 + kt * 32, lB0);
        gload_lds16(gb1 + kt * 32, lB1);
        __syncthreads();
        short8 a[4], b[4];
#pragma unroll
        for (int mt = 0; mt < 4; mt++)
            a[mt] = *(const short8*)&As[(mo + mt * 16 + fr) * 32 + fq * 8];
#pragma unroll
        for (int nt = 0; nt < 4; nt++)
            b[nt] = *(const short8*)&Bs[(no + nt * 16 + fr) * 32 + fq * 8];
#pragma unroll
        for (int nt = 0; nt < 4; nt++)
#pragma unroll
            for (int mt = 0; mt < 4; mt++)
                acc[nt][mt] = __builtin_amdgcn_mfma_f32_16x16x32_bf16(b[nt], a[mt], acc[nt][mt], 0, 0, 0);
        __syncthreads();
    }
    // thread holds rows r = mo+mt*16+fr (slot), cols n0+no+nt*16+fq*4+i (H)
#pragma unroll
    for (int mt = 0; mt < 4; mt++) {
        int r = m0 + mo + mt * 16 + fr;
        if (r < CAP) {
            size_t base = ((size_t)e * CAP + r) * HDIM + n0 + no;
#pragma unroll
            for (int nt = 0; nt < 4; nt++) {
                ushort4 o;
                o.x = f2bf(acc[nt][mt][0]);
                o.y = f2bf(acc[nt][mt][1]);
                o.z = f2bf(acc[nt][mt][2]);
                o.w = f2bf(acc[nt][mt][3]);
                *(ushort4*)&D[base + nt * 16 + fq * 4] = o;
            }
        }
    }
}

// ---------------- combine: out[t] = w0*D[loc0] + w1*D[loc1] ----------------
__global__ __launch_bounds__(256) void combine(const unsigned short* __restrict__ D,
                                               const int* __restrict__ loc,
                                               const float* __restrict__ rw,
                                               float* __restrict__ out) {
    const int t = blockIdx.x;
    const int h = threadIdx.x * 8;
    const int l0 = loc[2 * t], l1 = loc[2 * t + 1];
    const float w0 = rw[2 * t], w1 = rw[2 * t + 1];
    float acc[8];
#pragma unroll
    for (int i = 0; i < 8; i++) acc[i] = 0.f;
    if (l0 >= 0) {
        ushort8v v = *(const ushort8v*)&D[(size_t)l0 * HDIM + h];
#pragma unroll
        for (int i = 0; i < 8; i++) acc[i] = w0 * bf2f(v[i]);
    }
    if (l1 >= 0) {
        ushort8v v = *(const ushort8v*)&D[(size_t)l1 * HDIM + h];
#pragma unroll
        for (int i = 0; i < 8; i++) acc[i] += w1 * bf2f(v[i]);
    }
    float4 o0 = make_float4(acc[0], acc[1], acc[2], acc[3]);
    float4 o1 = make_float4(acc[4], acc[5], acc[6], acc[7]);
    *(float4*)&out[(size_t)t * HDIM + h] = o0;
    *(float4*)&out[(size_t)t * HDIM + h + 4] = o1;
}

extern "C" void kernel_launch(void* const* d_in, const int* in_sizes, int n_in,
                              void* d_out, int out_size, void* d_ws, size_t ws_size,
                              hipStream_t stream) {
    const float* x  = (const float*)d_in[0];
    const float* gw = (const float*)d_in[1];
    const float* w1 = (const float*)d_in[2];
    const float* w2 = (const float*)d_in[3];
    const float* w3 = (const float*)d_in[4];
    float* out = (float*)d_out;

    char* ws = (char*)d_ws;
    size_t off = 0;
    int* sel = (int*)(ws + off);                off += (size_t)T_TOK * 2 * 4;   // 128K
    int* loc = (int*)(ws + off);                off += (size_t)T_TOK * 2 * 4;   // 128K
    float* rw = (float*)(ws + off);             off += (size_t)T_TOK * 2 * 4;   // 128K
    int* tok = (int*)(ws + off);                off += 82176;                    // 12*1707*4 padded
    int* counts = (int*)(ws + off);             off += 4096;                     // 12*64*4 padded
    unsigned short* w2b = (unsigned short*)(ws + off); off += (size_t)NEXP * HDIM * FDIM * 2;
    unsigned short* G   = (unsigned short*)(ws + off); off += (size_t)NEXP * CAP * FDIM * 2;
    // aliased region R (98.5 MB): phase 1 = part+w1b+w3b+xb; phase 2 = D (84 MB)
    char* R = ws + off;
    float* part = (float*)R;                                                    // 6,291,456 B
    unsigned short* w1b = (unsigned short*)(R + 6291456);                       // 12,582,912 B
    unsigned short* w3b = (unsigned short*)(R + 6291456 + 12582912);            // 12,582,912 B
    unsigned short* xb  = (unsigned short*)(R + 6291456 + 2 * 12582912);        // 67,108,864 B
    unsigned short* D   = (unsigned short*)R;                                   // 83,902,464 B

    const int nw4 = NEXP * FDIM * HDIM / 4;

    cvt3<<<2048, 256, 0, stream>>>((const float4*)w1, (ushort4*)w1b,
                                   (const float4*)w3, (ushort4*)w3b,
                                   (const float4*)w2, (ushort4*)w2b, nw4);
    gating_partial<<<dim3(T_TOK / 8, 2), 256, 0, stream>>>(x, gw, part, (ushort4*)xb);
    gating_top2<<<T_TOK / 256, 256, 0, stream>>>(part, sel, rw);
    route_count<<<64, 512, 0, stream>>>(sel, counts);
    route_emit<<<dim3(64, NEXP), 512, 0, stream>>>(sel, counts, tok, loc);
    up_gemm<<<dim3(14, 4, NEXP), 256, 0, stream>>>(xb, w1b, w3b, tok, G);
    down_gemm<<<dim3(14, 16, NEXP), 256, 0, stream>>>(G, w2b, D);
    combine<<<T_TOK, 256, 0, stream>>>(D, loc, rw, out);
}